// Round 1
// baseline (966.304 us; speedup 1.0000x reference)
//
#include <hip/hip_runtime.h>
#include <hip/hip_bf16.h>

#define D_DIM 128
#define SCAN_T 1024

// ---------------- CSR build ----------------

__global__ void zero_cnt_kernel(int* __restrict__ cnt, int n) {
    int i = blockIdx.x * blockDim.x + threadIdx.x;
    if (i < n) cnt[i] = 0;
}

__global__ void count_kernel(const int* __restrict__ dst, int* __restrict__ cnt, int e) {
    int i = blockIdx.x * blockDim.x + threadIdx.x;
    if (i < e) atomicAdd(&cnt[dst[i]], 1);
}

// Single-block scan: cnt -> exclusive prefix (row_ptr, cursor), plus dinv = rsqrt(cnt+1).
__global__ void scan_kernel(const int* __restrict__ cnt, int* __restrict__ row_ptr,
                            int* __restrict__ cursor, float* __restrict__ dinv, int n) {
    __shared__ int part[SCAN_T];
    int t = threadIdx.x;
    int chunk = (n + SCAN_T - 1) / SCAN_T;
    int beg = t * chunk;
    int end = beg + chunk; if (end > n) end = n;
    int s = 0;
    for (int i = beg; i < end; ++i) s += cnt[i];
    part[t] = s;
    __syncthreads();
    // Hillis-Steele inclusive scan over 1024 partials
    for (int off = 1; off < SCAN_T; off <<= 1) {
        int val = (t >= off) ? part[t - off] : 0;
        __syncthreads();
        part[t] += val;
        __syncthreads();
    }
    int excl = (t == 0) ? 0 : part[t - 1];
    for (int i = beg; i < end; ++i) {
        int c = cnt[i];
        row_ptr[i] = excl;
        cursor[i]  = excl;
        dinv[i]    = rsqrtf((float)(c + 1));   // deg includes self loop
        excl += c;
    }
    if (t == SCAN_T - 1) row_ptr[n] = excl;
}

__global__ void fill_kernel(const int* __restrict__ src, const int* __restrict__ dst,
                            int* __restrict__ cursor, int* __restrict__ col, int e) {
    int i = blockIdx.x * blockDim.x + threadIdx.x;
    if (i < e) {
        int p = atomicAdd(&cursor[dst[i]], 1);
        col[p] = src[i];
    }
}

// ---------------- GEMM: H = X @ W  (f32 vector, SGPR-broadcast W) ----------------
// Block = 256 threads = 4 waves; block covers 64 rows. lane = row-in-tile.
// Wave w computes columns [w*32, w*32+32). W read via wave-uniform index -> s_load.
__global__ __launch_bounds__(256) void gemm_kernel(const float* __restrict__ X,
                                                   const float* __restrict__ W,
                                                   float* __restrict__ H, int n) {
    __shared__ float xT[D_DIM * 65];   // xT[k*65 + r]
    const int t = threadIdx.x;
    const int row0 = blockIdx.x * 64;

    // Stage 64 rows x 128 cols, transposed. 2048 float4 loads over 256 threads.
    #pragma unroll
    for (int i = 0; i < 8; ++i) {
        int q  = t + i * 256;     // float4 index
        int r  = q >> 5;          // row in tile [0,64)
        int k4 = q & 31;          // float4 index along k
        int row = row0 + r;
        float4 v = make_float4(0.f, 0.f, 0.f, 0.f);
        if (row < n) v = *(const float4*)(X + (size_t)row * D_DIM + k4 * 4);
        int k = k4 * 4;
        xT[(k + 0) * 65 + r] = v.x;
        xT[(k + 1) * 65 + r] = v.y;
        xT[(k + 2) * 65 + r] = v.z;
        xT[(k + 3) * 65 + r] = v.w;
    }
    __syncthreads();

    const int wave = __builtin_amdgcn_readfirstlane(t >> 6);  // force SGPR -> uniform W addrs
    const int lane = t & 63;
    const int c0 = wave * 32;

    float acc[32];
    #pragma unroll
    for (int j = 0; j < 32; ++j) acc[j] = 0.f;

    for (int k = 0; k < D_DIM; ++k) {
        float xv = xT[k * 65 + lane];
        const float* wr = W + (size_t)k * D_DIM + c0;   // uniform -> s_load
        #pragma unroll
        for (int j = 0; j < 32; ++j) acc[j] = fmaf(xv, wr[j], acc[j]);
    }

    int row = row0 + lane;
    if (row < n) {
        float* out = H + (size_t)row * D_DIM + c0;
        #pragma unroll
        for (int j = 0; j < 32; ++j) out[j] = acc[j];
    }
}

// ---------------- Aggregation + bias + ReLU + LayerNorm (one wave per node) ----------------
__global__ __launch_bounds__(256) void agg_kernel(const float* __restrict__ H,
                                                  const int* __restrict__ row_ptr,
                                                  const int* __restrict__ col,
                                                  const float* __restrict__ dinv,
                                                  const float* __restrict__ bias,
                                                  const float* __restrict__ gamma,
                                                  const float* __restrict__ beta,
                                                  float* __restrict__ Y, int n) {
    const int wave = __builtin_amdgcn_readfirstlane(threadIdx.x >> 6);
    const int lane = threadIdx.x & 63;
    const int v = blockIdx.x * 4 + wave;
    if (v >= n) return;

    const float dv = dinv[v];
    const float2* hvrow = (const float2*)(H + (size_t)v * D_DIM);
    float2 hs = hvrow[lane];
    float wself = dv * dv;
    float ax = hs.x * wself;
    float ay = hs.y * wself;

    const int beg = row_ptr[v];
    const int end = row_ptr[v + 1];
    for (int i = beg; i < end; ++i) {
        int u = col[i];                        // uniform -> s_load
        float wuv = dinv[u] * dv;
        const float2* hu = (const float2*)(H + (size_t)u * D_DIM);
        float2 h2 = hu[lane];
        ax = fmaf(wuv, h2.x, ax);
        ay = fmaf(wuv, h2.y, ay);
    }

    // bias + relu
    float2 bb = ((const float2*)bias)[lane];
    float a0 = fmaxf(ax + bb.x, 0.f);
    float a1 = fmaxf(ay + bb.y, 0.f);

    // layernorm over 128 values (2 per lane)
    float s1 = a0 + a1;
    float s2 = a0 * a0 + a1 * a1;
    #pragma unroll
    for (int m = 1; m < 64; m <<= 1) {
        s1 += __shfl_xor(s1, m, 64);
        s2 += __shfl_xor(s2, m, 64);
    }
    float mu  = s1 * (1.f / 128.f);
    float var = s2 * (1.f / 128.f) - mu * mu;
    float rs  = rsqrtf(var + 1e-5f);

    float2 gg = ((const float2*)gamma)[lane];
    float2 be = ((const float2*)beta)[lane];
    float2 o;
    o.x = (a0 - mu) * rs * gg.x + be.x;
    o.y = (a1 - mu) * rs * gg.y + be.y;
    ((float2*)(Y + (size_t)v * D_DIM))[lane] = o;
}

// ---------------- launch ----------------

extern "C" void kernel_launch(void* const* d_in, const int* in_sizes, int n_in,
                              void* d_out, int out_size, void* d_ws, size_t ws_size,
                              hipStream_t stream) {
    const float* x     = (const float*)d_in[0];
    const float* W     = (const float*)d_in[1];
    const float* bias  = (const float*)d_in[2];
    const float* gamma = (const float*)d_in[3];
    const float* beta  = (const float*)d_in[4];
    const int*   edges = (const int*)d_in[5];

    const int N = in_sizes[0] / D_DIM;
    const int E = in_sizes[5] / 2;
    const int L = in_sizes[1] / (D_DIM * D_DIM);

    const int* src = edges;
    const int* dst = edges + E;

    // workspace carve (all 256B-aligned enough: sizes are multiples of 4; big blocks first)
    char* w = (char*)d_ws;
    float* A    = (float*)w; w += (size_t)N * D_DIM * sizeof(float);   // GEMM output h
    float* Bbuf = (float*)w; w += (size_t)N * D_DIM * sizeof(float);   // activation ping-pong
    int* cnt     = (int*)w;  w += (size_t)N * sizeof(int);
    int* row_ptr = (int*)w;  w += (size_t)(N + 1) * sizeof(int);
    int* cursor  = (int*)w;  w += (size_t)N * sizeof(int);
    int* colArr  = (int*)w;  w += (size_t)E * sizeof(int);
    float* dinv  = (float*)w; w += (size_t)N * sizeof(float);

    // CSR build (per call: ws is re-poisoned)
    zero_cnt_kernel<<<(N + 255) / 256, 256, 0, stream>>>(cnt, N);
    count_kernel<<<(E + 255) / 256, 256, 0, stream>>>(dst, cnt, E);
    scan_kernel<<<1, SCAN_T, 0, stream>>>(cnt, row_ptr, cursor, dinv, N);
    fill_kernel<<<(E + 255) / 256, 256, 0, stream>>>(src, dst, cursor, colArr, E);

    // layers: act -> gemm -> A -> agg -> next act
    const float* act = x;
    float* outbufs[4] = {Bbuf, (float*)d_out, Bbuf, (float*)d_out};
    for (int l = 0; l < L; ++l) {
        gemm_kernel<<<(N + 63) / 64, 256, 0, stream>>>(act, W + (size_t)l * D_DIM * D_DIM, A, N);
        agg_kernel<<<(N + 3) / 4, 256, 0, stream>>>(A, row_ptr, colArr, dinv,
                                                    bias + (size_t)l * D_DIM,
                                                    gamma + (size_t)l * D_DIM,
                                                    beta + (size_t)l * D_DIM,
                                                    outbufs[l], N);
        act = outbufs[l];
    }
}

// Round 2
// 693.238 us; speedup vs baseline: 1.3939x; 1.3939x over previous
//
#include <hip/hip_runtime.h>
#include <hip/hip_bf16.h>

#define D_DIM 128

// ---------------- CSR build ----------------

__global__ void zero_cnt_kernel(int* __restrict__ cnt, int n) {
    int i = blockIdx.x * blockDim.x + threadIdx.x;
    if (i < n) cnt[i] = 0;
}

__global__ void count_kernel(const int* __restrict__ dst, int* __restrict__ cnt, int e) {
    int i = blockIdx.x * blockDim.x + threadIdx.x;
    if (i < e) atomicAdd(&cnt[dst[i]], 1);
}

// --- 3-kernel parallel exclusive scan over cnt[N] (1024 elements per block) ---

__global__ __launch_bounds__(256) void partial_kernel(const int* __restrict__ cnt,
                                                      int* __restrict__ partial, int n) {
    const int b = blockIdx.x, t = threadIdx.x;
    const int base = b * 1024 + t * 4;
    int s = 0;
    if (base + 3 < n) {
        int4 c = *(const int4*)(cnt + base);
        s = c.x + c.y + c.z + c.w;
    } else {
        for (int j = 0; j < 4; ++j) if (base + j < n) s += cnt[base + j];
    }
    #pragma unroll
    for (int m = 1; m < 64; m <<= 1) s += __shfl_xor(s, m, 64);
    __shared__ int ws[4];
    if ((t & 63) == 0) ws[t >> 6] = s;
    __syncthreads();
    if (t == 0) partial[b] = ws[0] + ws[1] + ws[2] + ws[3];
}

// One block: exclusive-scan the per-block partials in place. nb <= 1024.
__global__ __launch_bounds__(1024) void scan_partials_kernel(int* __restrict__ partial, int nb,
                                                             int* __restrict__ row_ptr,
                                                             int n, int e) {
    __shared__ int sh[1024];
    const int t = threadIdx.x;
    sh[t] = (t < nb) ? partial[t] : 0;
    __syncthreads();
    for (int off = 1; off < 1024; off <<= 1) {
        int v = (t >= off) ? sh[t - off] : 0;
        __syncthreads();
        sh[t] += v;
        __syncthreads();
    }
    if (t < nb) partial[t] = (t == 0) ? 0 : sh[t - 1];
    if (t == 0) row_ptr[n] = e;   // total real edges is exactly E
}

__global__ __launch_bounds__(256) void emit_kernel(const int* __restrict__ cnt,
                                                   const int* __restrict__ partial,
                                                   int* __restrict__ row_ptr,
                                                   int* __restrict__ cursor,
                                                   float* __restrict__ dinv, int n) {
    const int b = blockIdx.x, t = threadIdx.x;
    const int base = b * 1024 + t * 4;
    int4 c = make_int4(0, 0, 0, 0);
    if (base + 3 < n) {
        c = *(const int4*)(cnt + base);
    } else {
        if (base     < n) c.x = cnt[base];
        if (base + 1 < n) c.y = cnt[base + 1];
        if (base + 2 < n) c.z = cnt[base + 2];
        if (base + 3 < n) c.w = cnt[base + 3];
    }
    const int ts = c.x + c.y + c.z + c.w;
    // inclusive wave scan of per-thread sums
    int incl = ts;
    const int lane = t & 63;
    #pragma unroll
    for (int off = 1; off < 64; off <<= 1) {
        int v = __shfl_up(incl, off, 64);
        if (lane >= off) incl += v;
    }
    __shared__ int wsum[4];
    if (lane == 63) wsum[t >> 6] = incl;
    __syncthreads();
    const int w = t >> 6;
    int waveoff = 0;
    #pragma unroll
    for (int i = 0; i < 3; ++i) if (i < w) waveoff += wsum[i];
    const int basev = partial[b] + waveoff + (incl - ts);
    const int e0 = basev, e1 = e0 + c.x, e2 = e1 + c.y, e3 = e2 + c.z;
    if (base + 3 < n) {
        *(int4*)(row_ptr + base) = make_int4(e0, e1, e2, e3);
        *(int4*)(cursor  + base) = make_int4(e0, e1, e2, e3);
        *(float4*)(dinv + base) = make_float4(rsqrtf((float)(c.x + 1)), rsqrtf((float)(c.y + 1)),
                                              rsqrtf((float)(c.z + 1)), rsqrtf((float)(c.w + 1)));
    } else {
        int es[4] = {e0, e1, e2, e3};
        int cs[4] = {c.x, c.y, c.z, c.w};
        for (int j = 0; j < 4; ++j) if (base + j < n) {
            row_ptr[base + j] = es[j];
            cursor[base + j]  = es[j];
            dinv[base + j]    = rsqrtf((float)(cs[j] + 1));
        }
    }
}

__global__ void fill_kernel(const int* __restrict__ src, const int* __restrict__ dst,
                            int* __restrict__ cursor, int* __restrict__ col, int e) {
    int i = blockIdx.x * blockDim.x + threadIdx.x;
    if (i < e) {
        int p = atomicAdd(&cursor[dst[i]], 1);
        col[p] = src[i];
    }
}

// ---------------- GEMM: H = X @ W  (f32 vector, SGPR-broadcast W) ----------------
__global__ __launch_bounds__(256) void gemm_kernel(const float* __restrict__ X,
                                                   const float* __restrict__ W,
                                                   float* __restrict__ H, int n) {
    __shared__ float xT[D_DIM * 65];   // xT[k*65 + r]
    const int t = threadIdx.x;
    const int row0 = blockIdx.x * 64;

    #pragma unroll
    for (int i = 0; i < 8; ++i) {
        int q  = t + i * 256;     // float4 index
        int r  = q >> 5;          // row in tile [0,64)
        int k4 = q & 31;          // float4 index along k
        int row = row0 + r;
        float4 v = make_float4(0.f, 0.f, 0.f, 0.f);
        if (row < n) v = *(const float4*)(X + (size_t)row * D_DIM + k4 * 4);
        int k = k4 * 4;
        xT[(k + 0) * 65 + r] = v.x;
        xT[(k + 1) * 65 + r] = v.y;
        xT[(k + 2) * 65 + r] = v.z;
        xT[(k + 3) * 65 + r] = v.w;
    }
    __syncthreads();

    const int wave = __builtin_amdgcn_readfirstlane(t >> 6);  // force SGPR -> uniform W addrs
    const int lane = t & 63;
    const int c0 = wave * 32;

    float acc[32];
    #pragma unroll
    for (int j = 0; j < 32; ++j) acc[j] = 0.f;

    for (int k = 0; k < D_DIM; ++k) {
        float xv = xT[k * 65 + lane];
        const float* wr = W + (size_t)k * D_DIM + c0;   // uniform -> s_load
        #pragma unroll
        for (int j = 0; j < 32; ++j) acc[j] = fmaf(xv, wr[j], acc[j]);
    }

    int row = row0 + lane;
    if (row < n) {
        float* out = H + (size_t)row * D_DIM + c0;
        #pragma unroll
        for (int j = 0; j < 32; ++j) out[j] = acc[j];
    }
}

// ---------------- Aggregation + bias + ReLU + LayerNorm (one wave per node) ----------------
__global__ __launch_bounds__(256) void agg_kernel(const float* __restrict__ H,
                                                  const int* __restrict__ row_ptr,
                                                  const int* __restrict__ col,
                                                  const float* __restrict__ dinv,
                                                  const float* __restrict__ bias,
                                                  const float* __restrict__ gamma,
                                                  const float* __restrict__ beta,
                                                  float* __restrict__ Y, int n) {
    const int wave = __builtin_amdgcn_readfirstlane(threadIdx.x >> 6);
    const int lane = threadIdx.x & 63;
    const int v = blockIdx.x * 4 + wave;
    if (v >= n) return;

    const float dv = dinv[v];
    const float2* hvrow = (const float2*)(H + (size_t)v * D_DIM);
    float2 hs = hvrow[lane];
    float wself = dv * dv;
    float ax = hs.x * wself;
    float ay = hs.y * wself;

    const int beg = row_ptr[v];
    const int end = row_ptr[v + 1];
    for (int i = beg; i < end; ++i) {
        int u = col[i];
        float wuv = dinv[u] * dv;
        const float2* hu = (const float2*)(H + (size_t)u * D_DIM);
        float2 h2 = hu[lane];
        ax = fmaf(wuv, h2.x, ax);
        ay = fmaf(wuv, h2.y, ay);
    }

    // bias + relu
    float2 bb = ((const float2*)bias)[lane];
    float a0 = fmaxf(ax + bb.x, 0.f);
    float a1 = fmaxf(ay + bb.y, 0.f);

    // layernorm over 128 values (2 per lane)
    float s1 = a0 + a1;
    float s2 = a0 * a0 + a1 * a1;
    #pragma unroll
    for (int m = 1; m < 64; m <<= 1) {
        s1 += __shfl_xor(s1, m, 64);
        s2 += __shfl_xor(s2, m, 64);
    }
    float mu  = s1 * (1.f / 128.f);
    float var = s2 * (1.f / 128.f) - mu * mu;
    float rs  = rsqrtf(var + 1e-5f);

    float2 gg = ((const float2*)gamma)[lane];
    float2 be = ((const float2*)beta)[lane];
    float2 o;
    o.x = (a0 - mu) * rs * gg.x + be.x;
    o.y = (a1 - mu) * rs * gg.y + be.y;
    ((float2*)(Y + (size_t)v * D_DIM))[lane] = o;
}

// ---------------- launch ----------------

extern "C" void kernel_launch(void* const* d_in, const int* in_sizes, int n_in,
                              void* d_out, int out_size, void* d_ws, size_t ws_size,
                              hipStream_t stream) {
    const float* x     = (const float*)d_in[0];
    const float* W     = (const float*)d_in[1];
    const float* bias  = (const float*)d_in[2];
    const float* gamma = (const float*)d_in[3];
    const float* beta  = (const float*)d_in[4];
    const int*   edges = (const int*)d_in[5];

    const int N = in_sizes[0] / D_DIM;
    const int E = in_sizes[5] / 2;
    const int L = in_sizes[1] / (D_DIM * D_DIM);

    const int* src = edges;
    const int* dst = edges + E;

    const int NB = (N + 1023) / 1024;   // scan blocks

    // workspace carve — keep every region 16B-aligned (int4/float4 stores)
    char* w = (char*)d_ws;
    float* A    = (float*)w; w += (size_t)N * D_DIM * sizeof(float);   // GEMM output h
    float* Bbuf = (float*)w; w += (size_t)N * D_DIM * sizeof(float);   // activation ping-pong
    int* cnt     = (int*)w;  w += (size_t)((N + 3) & ~3) * sizeof(int);
    int* row_ptr = (int*)w;  w += (size_t)((N + 4) & ~3) * sizeof(int);
    int* cursor  = (int*)w;  w += (size_t)((N + 3) & ~3) * sizeof(int);
    int* colArr  = (int*)w;  w += (size_t)((E + 3) & ~3) * sizeof(int);
    float* dinv  = (float*)w; w += (size_t)((N + 3) & ~3) * sizeof(float);
    int* partial = (int*)w;  w += (size_t)((NB + 3) & ~3) * sizeof(int);

    // CSR build (per call: ws is re-poisoned)
    zero_cnt_kernel<<<(N + 255) / 256, 256, 0, stream>>>(cnt, N);
    count_kernel<<<(E + 255) / 256, 256, 0, stream>>>(dst, cnt, E);
    partial_kernel<<<NB, 256, 0, stream>>>(cnt, partial, N);
    scan_partials_kernel<<<1, 1024, 0, stream>>>(partial, NB, row_ptr, N, E);
    emit_kernel<<<NB, 256, 0, stream>>>(cnt, partial, row_ptr, cursor, dinv, N);
    fill_kernel<<<(E + 255) / 256, 256, 0, stream>>>(src, dst, cursor, colArr, E);

    // layers: act -> gemm -> A -> agg -> next act
    const float* act = x;
    float* outbufs[4] = {Bbuf, (float*)d_out, Bbuf, (float*)d_out};
    for (int l = 0; l < L; ++l) {
        gemm_kernel<<<(N + 63) / 64, 256, 0, stream>>>(act, W + (size_t)l * D_DIM * D_DIM, A, N);
        agg_kernel<<<(N + 3) / 4, 256, 0, stream>>>(A, row_ptr, colArr, dinv,
                                                    bias + (size_t)l * D_DIM,
                                                    gamma + (size_t)l * D_DIM,
                                                    beta + (size_t)l * D_DIM,
                                                    outbufs[l], N);
        act = outbufs[l];
    }
}

// Round 3
// 513.654 us; speedup vs baseline: 1.8812x; 1.3496x over previous
//
#include <hip/hip_runtime.h>
#include <hip/hip_bf16.h>

#define D_DIM 128
#define AST 136   // padded LDS row stride (shorts) for A and Wt tiles

typedef __attribute__((ext_vector_type(8))) short short8v;
typedef __attribute__((ext_vector_type(4))) short short4v;
typedef __attribute__((ext_vector_type(4))) float floatx4;

__device__ __forceinline__ short f2bf(float x) {
    unsigned u = __builtin_bit_cast(unsigned, x);
    unsigned r = u + 0x7fff + ((u >> 16) & 1);   // RNE
    return (short)(r >> 16);
}

// ---------------- CSR build ----------------

__global__ void zero_cnt_kernel(int* __restrict__ cnt, int n) {
    int i = blockIdx.x * blockDim.x + threadIdx.x;
    if (i < n) cnt[i] = 0;
}

__global__ void count_kernel(const int* __restrict__ dst, int* __restrict__ cnt, int e) {
    int i = blockIdx.x * blockDim.x + threadIdx.x;
    if (i < e) atomicAdd(&cnt[dst[i]], 1);
}

__global__ __launch_bounds__(256) void partial_kernel(const int* __restrict__ cnt,
                                                      int* __restrict__ partial, int n) {
    const int b = blockIdx.x, t = threadIdx.x;
    const int base = b * 1024 + t * 4;
    int s = 0;
    if (base + 3 < n) {
        int4 c = *(const int4*)(cnt + base);
        s = c.x + c.y + c.z + c.w;
    } else {
        for (int j = 0; j < 4; ++j) if (base + j < n) s += cnt[base + j];
    }
    #pragma unroll
    for (int m = 1; m < 64; m <<= 1) s += __shfl_xor(s, m, 64);
    __shared__ int ws[4];
    if ((t & 63) == 0) ws[t >> 6] = s;
    __syncthreads();
    if (t == 0) partial[b] = ws[0] + ws[1] + ws[2] + ws[3];
}

__global__ __launch_bounds__(1024) void scan_partials_kernel(int* __restrict__ partial, int nb,
                                                             int* __restrict__ row_ptr,
                                                             int n, int e) {
    __shared__ int sh[1024];
    const int t = threadIdx.x;
    sh[t] = (t < nb) ? partial[t] : 0;
    __syncthreads();
    for (int off = 1; off < 1024; off <<= 1) {
        int v = (t >= off) ? sh[t - off] : 0;
        __syncthreads();
        sh[t] += v;
        __syncthreads();
    }
    if (t < nb) partial[t] = (t == 0) ? 0 : sh[t - 1];
    if (t == 0) row_ptr[n] = e;
}

__global__ __launch_bounds__(256) void emit_kernel(const int* __restrict__ cnt,
                                                   const int* __restrict__ partial,
                                                   int* __restrict__ row_ptr,
                                                   int* __restrict__ cursor,
                                                   float* __restrict__ dinv, int n) {
    const int b = blockIdx.x, t = threadIdx.x;
    const int base = b * 1024 + t * 4;
    int4 c = make_int4(0, 0, 0, 0);
    if (base + 3 < n) {
        c = *(const int4*)(cnt + base);
    } else {
        if (base     < n) c.x = cnt[base];
        if (base + 1 < n) c.y = cnt[base + 1];
        if (base + 2 < n) c.z = cnt[base + 2];
        if (base + 3 < n) c.w = cnt[base + 3];
    }
    const int ts = c.x + c.y + c.z + c.w;
    int incl = ts;
    const int lane = t & 63;
    #pragma unroll
    for (int off = 1; off < 64; off <<= 1) {
        int v = __shfl_up(incl, off, 64);
        if (lane >= off) incl += v;
    }
    __shared__ int wsum[4];
    if (lane == 63) wsum[t >> 6] = incl;
    __syncthreads();
    const int w = t >> 6;
    int waveoff = 0;
    #pragma unroll
    for (int i = 0; i < 3; ++i) if (i < w) waveoff += wsum[i];
    const int basev = partial[b] + waveoff + (incl - ts);
    const int e0 = basev, e1 = e0 + c.x, e2 = e1 + c.y, e3 = e2 + c.z;
    if (base + 3 < n) {
        *(int4*)(row_ptr + base) = make_int4(e0, e1, e2, e3);
        *(int4*)(cursor  + base) = make_int4(e0, e1, e2, e3);
        *(float4*)(dinv + base) = make_float4(rsqrtf((float)(c.x + 1)), rsqrtf((float)(c.y + 1)),
                                              rsqrtf((float)(c.z + 1)), rsqrtf((float)(c.w + 1)));
    } else {
        int es[4] = {e0, e1, e2, e3};
        int cs[4] = {c.x, c.y, c.z, c.w};
        for (int j = 0; j < 4; ++j) if (base + j < n) {
            row_ptr[base + j] = es[j];
            cursor[base + j]  = es[j];
            dinv[base + j]    = rsqrtf((float)(cs[j] + 1));
        }
    }
}

__global__ void fill_kernel(const int* __restrict__ src, const int* __restrict__ dst,
                            int* __restrict__ cursor, int* __restrict__ col, int e) {
    int i = blockIdx.x * blockDim.x + threadIdx.x;
    if (i < e) {
        int p = atomicAdd(&cursor[dst[i]], 1);
        col[p] = src[i];
    }
}

// ---------------- W transpose+convert: Wt[l][n][k] = bf16(W[l][k][n]) ----------------
__global__ __launch_bounds__(256) void wt_prep_kernel(const float* __restrict__ W,
                                                      short* __restrict__ Wt, int total) {
    int o = blockIdx.x * blockDim.x + threadIdx.x;
    if (o >= total) return;
    int l = o >> 14;
    int r = o & 16383;
    int nn = r >> 7;
    int k  = r & 127;
    Wt[o] = f2bf(W[(size_t)l * 16384 + (size_t)k * 128 + nn]);
}

// ---------------- GEMM: H = X @ W via bf16 MFMA ----------------
// Block = 256 threads = 4 waves; tile 64 rows x 128 cols. Wave w: rows [w*16, w*16+16).
__global__ __launch_bounds__(256) void gemm_mfma_kernel(const float* __restrict__ X,
                                                        const short* __restrict__ Wt,
                                                        float* __restrict__ H, int n) {
    __shared__ short Alds[64 * AST];    // A[r][k] bf16, padded
    __shared__ short Wlds[128 * AST];   // Wt[n][k] bf16, padded
    const int t = threadIdx.x;
    const int row0 = blockIdx.x * 64;

    // stage Wt (32 KB, coalesced 16B chunks)
    #pragma unroll
    for (int i = 0; i < 8; ++i) {
        int q  = t + i * 256;     // ushort8 chunk id (2048)
        int nn = q >> 4;          // 0..127
        int kc = q & 15;          // 0..15
        short8v v = *(const short8v*)(Wt + nn * 128 + kc * 8);
        *(short8v*)(&Wlds[nn * AST + kc * 8]) = v;
    }
    // stage A: 64 rows x 128 f32 -> bf16
    #pragma unroll
    for (int i = 0; i < 8; ++i) {
        int q  = t + i * 256;     // float4 id (2048)
        int r  = q >> 5;
        int k4 = q & 31;
        int row = row0 + r;
        float4 v = make_float4(0.f, 0.f, 0.f, 0.f);
        if (row < n) v = *(const float4*)(X + (size_t)row * D_DIM + k4 * 4);
        short4v s;
        s.x = f2bf(v.x); s.y = f2bf(v.y); s.z = f2bf(v.z); s.w = f2bf(v.w);
        *(short4v*)(&Alds[r * AST + k4 * 4]) = s;
    }
    __syncthreads();

    const int wv   = t >> 6;
    const int lane = t & 63;
    const int m    = lane & 15;
    const int quad = lane >> 4;

    const short* abase = &Alds[(wv * 16 + m) * AST + quad * 8];
    const short* bbase = &Wlds[m * AST + quad * 8];

    short8v afr[4];
    #pragma unroll
    for (int kt = 0; kt < 4; ++kt) afr[kt] = *(const short8v*)(abase + kt * 32);

    floatx4 acc[8];
    #pragma unroll
    for (int c = 0; c < 8; ++c) acc[c] = (floatx4){0.f, 0.f, 0.f, 0.f};

    #pragma unroll
    for (int c = 0; c < 8; ++c) {
        #pragma unroll
        for (int kt = 0; kt < 4; ++kt) {
            short8v bfr = *(const short8v*)(bbase + c * 16 * AST + kt * 32);
            acc[c] = __builtin_amdgcn_mfma_f32_16x16x32_bf16(afr[kt], bfr, acc[c], 0, 0, 0);
        }
    }

    // C/D layout: col = lane&15, row = quad*4 + reg   [m89-verified]
    #pragma unroll
    for (int c = 0; c < 8; ++c) {
        #pragma unroll
        for (int r = 0; r < 4; ++r) {
            int row = row0 + wv * 16 + quad * 4 + r;
            if (row < n) H[(size_t)row * D_DIM + c * 16 + m] = acc[c][r];
        }
    }
}

// ---------------- Aggregation + bias + ReLU + LayerNorm (one wave per node) ----------------
__global__ __launch_bounds__(256) void agg_kernel(const float* __restrict__ H,
                                                  const int* __restrict__ row_ptr,
                                                  const int* __restrict__ col,
                                                  const float* __restrict__ dinv,
                                                  const float* __restrict__ bias,
                                                  const float* __restrict__ gamma,
                                                  const float* __restrict__ beta,
                                                  float* __restrict__ Y, int n) {
    const int wave = __builtin_amdgcn_readfirstlane(threadIdx.x >> 6);
    const int lane = threadIdx.x & 63;
    const int v = blockIdx.x * 4 + wave;
    if (v >= n) return;

    const float dv = dinv[v];
    const float2* hvrow = (const float2*)(H + (size_t)v * D_DIM);
    float2 hs = hvrow[lane];
    float wself = dv * dv;
    float ax = hs.x * wself;
    float ay = hs.y * wself;

    const int beg = row_ptr[v];
    const int end = row_ptr[v + 1];
    for (int i = beg; i < end; ++i) {
        int u = col[i];
        float wuv = dinv[u] * dv;
        const float2* hu = (const float2*)(H + (size_t)u * D_DIM);
        float2 h2 = hu[lane];
        ax = fmaf(wuv, h2.x, ax);
        ay = fmaf(wuv, h2.y, ay);
    }

    float2 bb = ((const float2*)bias)[lane];
    float a0 = fmaxf(ax + bb.x, 0.f);
    float a1 = fmaxf(ay + bb.y, 0.f);

    float s1 = a0 + a1;
    float s2 = a0 * a0 + a1 * a1;
    #pragma unroll
    for (int m = 1; m < 64; m <<= 1) {
        s1 += __shfl_xor(s1, m, 64);
        s2 += __shfl_xor(s2, m, 64);
    }
    float mu  = s1 * (1.f / 128.f);
    float var = s2 * (1.f / 128.f) - mu * mu;
    float rs  = rsqrtf(var + 1e-5f);

    float2 gg = ((const float2*)gamma)[lane];
    float2 be = ((const float2*)beta)[lane];
    float2 o;
    o.x = (a0 - mu) * rs * gg.x + be.x;
    o.y = (a1 - mu) * rs * gg.y + be.y;
    ((float2*)(Y + (size_t)v * D_DIM))[lane] = o;
}

// ---------------- launch ----------------

extern "C" void kernel_launch(void* const* d_in, const int* in_sizes, int n_in,
                              void* d_out, int out_size, void* d_ws, size_t ws_size,
                              hipStream_t stream) {
    const float* x     = (const float*)d_in[0];
    const float* W     = (const float*)d_in[1];
    const float* bias  = (const float*)d_in[2];
    const float* gamma = (const float*)d_in[3];
    const float* beta  = (const float*)d_in[4];
    const int*   edges = (const int*)d_in[5];

    const int N = in_sizes[0] / D_DIM;
    const int E = in_sizes[5] / 2;
    const int L = in_sizes[1] / (D_DIM * D_DIM);

    const int* src = edges;
    const int* dst = edges + E;

    const int NB = (N + 1023) / 1024;

    // workspace carve — 16B alignment maintained
    char* w = (char*)d_ws;
    float* A    = (float*)w; w += (size_t)N * D_DIM * sizeof(float);
    float* Bbuf = (float*)w; w += (size_t)N * D_DIM * sizeof(float);
    int* cnt     = (int*)w;  w += (size_t)((N + 3) & ~3) * sizeof(int);
    int* row_ptr = (int*)w;  w += (size_t)((N + 4) & ~3) * sizeof(int);
    int* cursor  = (int*)w;  w += (size_t)((N + 3) & ~3) * sizeof(int);
    int* colArr  = (int*)w;  w += (size_t)((E + 3) & ~3) * sizeof(int);
    float* dinv  = (float*)w; w += (size_t)((N + 3) & ~3) * sizeof(float);
    int* partial = (int*)w;  w += (size_t)((NB + 3) & ~3) * sizeof(int);
    short* Wt    = (short*)w; w += (size_t)L * D_DIM * D_DIM * sizeof(short);

    // CSR build
    zero_cnt_kernel<<<(N + 255) / 256, 256, 0, stream>>>(cnt, N);
    count_kernel<<<(E + 255) / 256, 256, 0, stream>>>(dst, cnt, E);
    partial_kernel<<<NB, 256, 0, stream>>>(cnt, partial, N);
    scan_partials_kernel<<<1, 1024, 0, stream>>>(partial, NB, row_ptr, N, E);
    emit_kernel<<<NB, 256, 0, stream>>>(cnt, partial, row_ptr, cursor, dinv, N);
    fill_kernel<<<(E + 255) / 256, 256, 0, stream>>>(src, dst, cursor, colArr, E);

    // W -> bf16 transpose (once per call)
    const int WT_TOTAL = L * D_DIM * D_DIM;
    wt_prep_kernel<<<(WT_TOTAL + 255) / 256, 256, 0, stream>>>(W, Wt, WT_TOTAL);

    // layers
    const float* act = x;
    float* outbufs[4] = {Bbuf, (float*)d_out, Bbuf, (float*)d_out};
    for (int l = 0; l < L; ++l) {
        gemm_mfma_kernel<<<(N + 63) / 64, 256, 0, stream>>>(act, Wt + (size_t)l * D_DIM * D_DIM, A, N);
        agg_kernel<<<(N + 3) / 4, 256, 0, stream>>>(A, row_ptr, colArr, dinv,
                                                    bias + (size_t)l * D_DIM,
                                                    gamma + (size_t)l * D_DIM,
                                                    beta + (size_t)l * D_DIM,
                                                    outbufs[l], N);
        act = outbufs[l];
    }
}

// Round 4
// 456.679 us; speedup vs baseline: 2.1159x; 1.1248x over previous
//
#include <hip/hip_runtime.h>
#include <hip/hip_bf16.h>

#define D_DIM 128
#define AST 136   // padded LDS row stride (shorts)

typedef __attribute__((ext_vector_type(8))) short short8v;
typedef __attribute__((ext_vector_type(4))) short short4v;
typedef __attribute__((ext_vector_type(4))) float floatx4;

__device__ __forceinline__ short f2bf(float x) {
    unsigned u = __builtin_bit_cast(unsigned, x);
    unsigned r = u + 0x7fff + ((u >> 16) & 1);   // RNE
    return (short)(r >> 16);
}
__device__ __forceinline__ float bflo(unsigned p) {   // low bf16 of packed pair
    return __builtin_bit_cast(float, p << 16);
}
__device__ __forceinline__ float bfhi(unsigned p) {   // high bf16
    return __builtin_bit_cast(float, p & 0xffff0000u);
}

// ---------------- CSR build ----------------

__global__ void zero_cnt_kernel(int* __restrict__ cnt, int n) {
    int i = blockIdx.x * blockDim.x + threadIdx.x;
    if (i < n) cnt[i] = 0;
}

__global__ void count_kernel(const int* __restrict__ dst, int* __restrict__ cnt, int e) {
    int i = blockIdx.x * blockDim.x + threadIdx.x;
    if (i < e) atomicAdd(&cnt[dst[i]], 1);
}

__global__ __launch_bounds__(256) void partial_kernel(const int* __restrict__ cnt,
                                                      int* __restrict__ partial, int n) {
    const int b = blockIdx.x, t = threadIdx.x;
    const int base = b * 1024 + t * 4;
    int s = 0;
    if (base + 3 < n) {
        int4 c = *(const int4*)(cnt + base);
        s = c.x + c.y + c.z + c.w;
    } else {
        for (int j = 0; j < 4; ++j) if (base + j < n) s += cnt[base + j];
    }
    #pragma unroll
    for (int m = 1; m < 64; m <<= 1) s += __shfl_xor(s, m, 64);
    __shared__ int ws[4];
    if ((t & 63) == 0) ws[t >> 6] = s;
    __syncthreads();
    if (t == 0) partial[b] = ws[0] + ws[1] + ws[2] + ws[3];
}

__global__ __launch_bounds__(1024) void scan_partials_kernel(int* __restrict__ partial, int nb,
                                                             int* __restrict__ row_ptr,
                                                             int n, int e) {
    __shared__ int sh[1024];
    const int t = threadIdx.x;
    sh[t] = (t < nb) ? partial[t] : 0;
    __syncthreads();
    for (int off = 1; off < 1024; off <<= 1) {
        int v = (t >= off) ? sh[t - off] : 0;
        __syncthreads();
        sh[t] += v;
        __syncthreads();
    }
    if (t < nb) partial[t] = (t == 0) ? 0 : sh[t - 1];
    if (t == 0) row_ptr[n] = e;
}

__global__ __launch_bounds__(256) void emit_kernel(const int* __restrict__ cnt,
                                                   const int* __restrict__ partial,
                                                   int* __restrict__ row_ptr,
                                                   int* __restrict__ cursor,
                                                   float* __restrict__ dinv, int n) {
    const int b = blockIdx.x, t = threadIdx.x;
    const int base = b * 1024 + t * 4;
    int4 c = make_int4(0, 0, 0, 0);
    if (base + 3 < n) {
        c = *(const int4*)(cnt + base);
    } else {
        if (base     < n) c.x = cnt[base];
        if (base + 1 < n) c.y = cnt[base + 1];
        if (base + 2 < n) c.z = cnt[base + 2];
        if (base + 3 < n) c.w = cnt[base + 3];
    }
    const int ts = c.x + c.y + c.z + c.w;
    int incl = ts;
    const int lane = t & 63;
    #pragma unroll
    for (int off = 1; off < 64; off <<= 1) {
        int v = __shfl_up(incl, off, 64);
        if (lane >= off) incl += v;
    }
    __shared__ int wsum[4];
    if (lane == 63) wsum[t >> 6] = incl;
    __syncthreads();
    const int w = t >> 6;
    int waveoff = 0;
    #pragma unroll
    for (int i = 0; i < 3; ++i) if (i < w) waveoff += wsum[i];
    const int basev = partial[b] + waveoff + (incl - ts);
    const int e0 = basev, e1 = e0 + c.x, e2 = e1 + c.y, e3 = e2 + c.z;
    if (base + 3 < n) {
        *(int4*)(row_ptr + base) = make_int4(e0, e1, e2, e3);
        *(int4*)(cursor  + base) = make_int4(e0, e1, e2, e3);
        *(float4*)(dinv + base) = make_float4(rsqrtf((float)(c.x + 1)), rsqrtf((float)(c.y + 1)),
                                              rsqrtf((float)(c.z + 1)), rsqrtf((float)(c.w + 1)));
    } else {
        int es[4] = {e0, e1, e2, e3};
        int cs[4] = {c.x, c.y, c.z, c.w};
        for (int j = 0; j < 4; ++j) if (base + j < n) {
            row_ptr[base + j] = es[j];
            cursor[base + j]  = es[j];
            dinv[base + j]    = rsqrtf((float)(cs[j] + 1));
        }
    }
}

__global__ void fill_kernel(const int* __restrict__ src, const int* __restrict__ dst,
                            int* __restrict__ cursor, int* __restrict__ col, int e) {
    int i = blockIdx.x * blockDim.x + threadIdx.x;
    if (i < e) {
        int p = atomicAdd(&cursor[dst[i]], 1);
        col[p] = src[i];
    }
}

// ---------------- W transpose+convert: Wt[l][n][k] = bf16(W[l][k][n]) ----------------
__global__ __launch_bounds__(256) void wt_prep_kernel(const float* __restrict__ W,
                                                      short* __restrict__ Wt, int total) {
    int o = blockIdx.x * blockDim.x + threadIdx.x;
    if (o >= total) return;
    int l = o >> 14;
    int r = o & 16383;
    int nn = r >> 7;
    int k  = r & 127;
    Wt[o] = f2bf(W[(size_t)l * 16384 + (size_t)k * 128 + nn]);
}

// ---------------- GEMM: H(bf16) = act @ W via bf16 MFMA ----------------
// IN_F32: act is f32 (layer 0); else act is bf16 (layers 1..3).
template <bool IN_F32>
__global__ __launch_bounds__(256) void gemm_mfma_kernel(const void* __restrict__ Xv,
                                                        const short* __restrict__ Wt,
                                                        short* __restrict__ H, int n) {
    __shared__ short Alds[64 * AST];
    __shared__ short Wlds[128 * AST];
    const int t = threadIdx.x;
    const int row0 = blockIdx.x * 64;

    // stage Wt (32 KB)
    #pragma unroll
    for (int i = 0; i < 8; ++i) {
        int q  = t + i * 256;
        int nn = q >> 4;
        int kc = q & 15;
        short8v v = *(const short8v*)(Wt + nn * 128 + kc * 8);
        *(short8v*)(&Wlds[nn * AST + kc * 8]) = v;
    }
    // stage A
    if constexpr (IN_F32) {
        const float* X = (const float*)Xv;
        #pragma unroll
        for (int i = 0; i < 8; ++i) {
            int q  = t + i * 256;     // float4 id
            int r  = q >> 5;
            int k4 = q & 31;
            int row = row0 + r;
            float4 v = make_float4(0.f, 0.f, 0.f, 0.f);
            if (row < n) v = *(const float4*)(X + (size_t)row * D_DIM + k4 * 4);
            short4v s;
            s.x = f2bf(v.x); s.y = f2bf(v.y); s.z = f2bf(v.z); s.w = f2bf(v.w);
            *(short4v*)(&Alds[r * AST + k4 * 4]) = s;
        }
    } else {
        const short* X = (const short*)Xv;
        #pragma unroll
        for (int i = 0; i < 4; ++i) {
            int q  = t + i * 256;     // short8 id (1024)
            int r  = q >> 4;
            int kc = q & 15;
            int row = row0 + r;
            short8v v = {0,0,0,0,0,0,0,0};
            if (row < n) v = *(const short8v*)(X + (size_t)row * D_DIM + kc * 8);
            *(short8v*)(&Alds[r * AST + kc * 8]) = v;
        }
    }
    __syncthreads();

    const int wv   = t >> 6;
    const int lane = t & 63;
    const int m    = lane & 15;
    const int quad = lane >> 4;

    const short* abase = &Alds[(wv * 16 + m) * AST + quad * 8];
    const short* bbase = &Wlds[m * AST + quad * 8];

    short8v afr[4];
    #pragma unroll
    for (int kt = 0; kt < 4; ++kt) afr[kt] = *(const short8v*)(abase + kt * 32);

    floatx4 acc[8];
    #pragma unroll
    for (int c = 0; c < 8; ++c) acc[c] = (floatx4){0.f, 0.f, 0.f, 0.f};

    #pragma unroll
    for (int c = 0; c < 8; ++c) {
        #pragma unroll
        for (int kt = 0; kt < 4; ++kt) {
            short8v bfr = *(const short8v*)(bbase + c * 16 * AST + kt * 32);
            acc[c] = __builtin_amdgcn_mfma_f32_16x16x32_bf16(afr[kt], bfr, acc[c], 0, 0, 0);
        }
    }

    // C/D layout: col = lane&15, row = quad*4 + reg
    #pragma unroll
    for (int c = 0; c < 8; ++c) {
        #pragma unroll
        for (int r = 0; r < 4; ++r) {
            int row = row0 + wv * 16 + quad * 4 + r;
            if (row < n) H[(size_t)row * D_DIM + c * 16 + m] = f2bf(acc[c][r]);
        }
    }
}

// ---------------- Aggregation + bias + ReLU + LayerNorm ----------------
// H is bf16. OUT_BF16: write bf16 act (inner layers) else f32 (final -> d_out).
template <bool OUT_BF16>
__global__ __launch_bounds__(256) void agg_kernel(const short* __restrict__ Hb,
                                                  const int* __restrict__ row_ptr,
                                                  const int* __restrict__ col,
                                                  const float* __restrict__ dinv,
                                                  const float* __restrict__ bias,
                                                  const float* __restrict__ gamma,
                                                  const float* __restrict__ beta,
                                                  void* __restrict__ Yv, int n) {
    const int wave = __builtin_amdgcn_readfirstlane(threadIdx.x >> 6);
    const int lane = threadIdx.x & 63;
    const int v = blockIdx.x * 4 + wave;
    if (v >= n) return;

    const float dv = dinv[v];
    const unsigned* hv = (const unsigned*)(Hb + (size_t)v * D_DIM);
    unsigned ps = hv[lane];
    float wself = dv * dv;
    float ax = bflo(ps) * wself;
    float ay = bfhi(ps) * wself;

    const int beg = row_ptr[v];
    const int end = row_ptr[v + 1];
    for (int i = beg; i < end; ++i) {
        int u = col[i];
        float wuv = dinv[u] * dv;
        const unsigned* hu = (const unsigned*)(Hb + (size_t)u * D_DIM);
        unsigned p = hu[lane];
        ax = fmaf(wuv, bflo(p), ax);
        ay = fmaf(wuv, bfhi(p), ay);
    }

    float2 bb = ((const float2*)bias)[lane];
    float a0 = fmaxf(ax + bb.x, 0.f);
    float a1 = fmaxf(ay + bb.y, 0.f);

    float s1 = a0 + a1;
    float s2 = a0 * a0 + a1 * a1;
    #pragma unroll
    for (int m = 1; m < 64; m <<= 1) {
        s1 += __shfl_xor(s1, m, 64);
        s2 += __shfl_xor(s2, m, 64);
    }
    float mu  = s1 * (1.f / 128.f);
    float var = s2 * (1.f / 128.f) - mu * mu;
    float rs  = rsqrtf(var + 1e-5f);

    float2 gg = ((const float2*)gamma)[lane];
    float2 be = ((const float2*)beta)[lane];
    float o0 = (a0 - mu) * rs * gg.x + be.x;
    float o1 = (a1 - mu) * rs * gg.y + be.y;

    if constexpr (OUT_BF16) {
        unsigned pack = (unsigned)(unsigned short)f2bf(o0) |
                        ((unsigned)(unsigned short)f2bf(o1) << 16);
        ((unsigned*)((short*)Yv + (size_t)v * D_DIM))[lane] = pack;
    } else {
        float2 o; o.x = o0; o.y = o1;
        ((float2*)((float*)Yv + (size_t)v * D_DIM))[lane] = o;
    }
}

// ---------------- launch ----------------

extern "C" void kernel_launch(void* const* d_in, const int* in_sizes, int n_in,
                              void* d_out, int out_size, void* d_ws, size_t ws_size,
                              hipStream_t stream) {
    const float* x     = (const float*)d_in[0];
    const float* W     = (const float*)d_in[1];
    const float* bias  = (const float*)d_in[2];
    const float* gamma = (const float*)d_in[3];
    const float* beta  = (const float*)d_in[4];
    const int*   edges = (const int*)d_in[5];

    const int N = in_sizes[0] / D_DIM;
    const int E = in_sizes[5] / 2;
    const int L = in_sizes[1] / (D_DIM * D_DIM);

    const int* src = edges;
    const int* dst = edges + E;

    const int NB = (N + 1023) / 1024;

    // workspace carve — 16B alignment maintained
    char* w = (char*)d_ws;
    short* Hb   = (short*)w; w += (size_t)N * D_DIM * sizeof(short);   // gemm out (bf16)
    short* Act  = (short*)w; w += (size_t)N * D_DIM * sizeof(short);   // inter-layer act (bf16)
    int* cnt     = (int*)w;  w += (size_t)((N + 3) & ~3) * sizeof(int);
    int* row_ptr = (int*)w;  w += (size_t)((N + 4) & ~3) * sizeof(int);
    int* cursor  = (int*)w;  w += (size_t)((N + 3) & ~3) * sizeof(int);
    int* colArr  = (int*)w;  w += (size_t)((E + 3) & ~3) * sizeof(int);
    float* dinv  = (float*)w; w += (size_t)((N + 3) & ~3) * sizeof(float);
    int* partial = (int*)w;  w += (size_t)((NB + 3) & ~3) * sizeof(int);
    short* Wt    = (short*)w; w += (size_t)L * D_DIM * D_DIM * sizeof(short);

    // CSR build
    zero_cnt_kernel<<<(N + 255) / 256, 256, 0, stream>>>(cnt, N);
    count_kernel<<<(E + 255) / 256, 256, 0, stream>>>(dst, cnt, E);
    partial_kernel<<<NB, 256, 0, stream>>>(cnt, partial, N);
    scan_partials_kernel<<<1, 1024, 0, stream>>>(partial, NB, row_ptr, N, E);
    emit_kernel<<<NB, 256, 0, stream>>>(cnt, partial, row_ptr, cursor, dinv, N);
    fill_kernel<<<(E + 255) / 256, 256, 0, stream>>>(src, dst, cursor, colArr, E);

    // W -> bf16 transpose (once per call)
    const int WT_TOTAL = L * D_DIM * D_DIM;
    wt_prep_kernel<<<(WT_TOTAL + 255) / 256, 256, 0, stream>>>(W, Wt, WT_TOTAL);

    const int GB = (N + 63) / 64;
    const int AB = (N + 3) / 4;

    // layer 0: f32 x -> H(bf16) -> Act(bf16)
    gemm_mfma_kernel<true><<<GB, 256, 0, stream>>>(x, Wt, Hb, N);
    agg_kernel<true><<<AB, 256, 0, stream>>>(Hb, row_ptr, colArr, dinv,
                                             bias, gamma, beta, Act, N);
    // layers 1..L-2: bf16 -> bf16
    for (int l = 1; l < L - 1; ++l) {
        gemm_mfma_kernel<false><<<GB, 256, 0, stream>>>(Act, Wt + (size_t)l * D_DIM * D_DIM, Hb, N);
        agg_kernel<true><<<AB, 256, 0, stream>>>(Hb, row_ptr, colArr, dinv,
                                                 bias + (size_t)l * D_DIM,
                                                 gamma + (size_t)l * D_DIM,
                                                 beta + (size_t)l * D_DIM, Act, N);
    }
    // final layer: bf16 -> f32 d_out
    {
        int l = L - 1;
        gemm_mfma_kernel<false><<<GB, 256, 0, stream>>>(Act, Wt + (size_t)l * D_DIM * D_DIM, Hb, N);
        agg_kernel<false><<<AB, 256, 0, stream>>>(Hb, row_ptr, colArr, dinv,
                                                  bias + (size_t)l * D_DIM,
                                                  gamma + (size_t)l * D_DIM,
                                                  beta + (size_t)l * D_DIM, d_out, N);
    }
}

// Round 5
// 427.379 us; speedup vs baseline: 2.2610x; 1.0686x over previous
//
#include <hip/hip_runtime.h>
#include <hip/hip_bf16.h>

#define D_DIM 128
#define AST 136   // padded LDS row stride (shorts)
#define NPW 8     // nodes per wave in agg

typedef __attribute__((ext_vector_type(8))) short short8v;
typedef __attribute__((ext_vector_type(4))) short short4v;
typedef __attribute__((ext_vector_type(4))) float floatx4;

__device__ __forceinline__ short f2bf(float x) {
    unsigned u = __builtin_bit_cast(unsigned, x);
    unsigned r = u + 0x7fff + ((u >> 16) & 1);   // RNE
    return (short)(r >> 16);
}
__device__ __forceinline__ float bflo(unsigned p) {
    return __builtin_bit_cast(float, p << 16);
}
__device__ __forceinline__ float bfhi(unsigned p) {
    return __builtin_bit_cast(float, p & 0xffff0000u);
}

// ---------------- CSR build ----------------

__global__ void zero_cnt_kernel(int* __restrict__ cnt, int n) {
    int i = blockIdx.x * blockDim.x + threadIdx.x;
    if (i < n) cnt[i] = 0;
}

__global__ void count_kernel(const int* __restrict__ dst, int* __restrict__ cnt, int e) {
    int i = blockIdx.x * blockDim.x + threadIdx.x;
    if (i < e) atomicAdd(&cnt[dst[i]], 1);
}

__global__ __launch_bounds__(256) void partial_kernel(const int* __restrict__ cnt,
                                                      int* __restrict__ partial, int n) {
    const int b = blockIdx.x, t = threadIdx.x;
    const int base = b * 1024 + t * 4;
    int s = 0;
    if (base + 3 < n) {
        int4 c = *(const int4*)(cnt + base);
        s = c.x + c.y + c.z + c.w;
    } else {
        for (int j = 0; j < 4; ++j) if (base + j < n) s += cnt[base + j];
    }
    #pragma unroll
    for (int m = 1; m < 64; m <<= 1) s += __shfl_xor(s, m, 64);
    __shared__ int ws[4];
    if ((t & 63) == 0) ws[t >> 6] = s;
    __syncthreads();
    if (t == 0) partial[b] = ws[0] + ws[1] + ws[2] + ws[3];
}

__global__ __launch_bounds__(1024) void scan_partials_kernel(int* __restrict__ partial, int nb,
                                                             int* __restrict__ row_ptr,
                                                             int n, int e) {
    __shared__ int sh[1024];
    const int t = threadIdx.x;
    sh[t] = (t < nb) ? partial[t] : 0;
    __syncthreads();
    for (int off = 1; off < 1024; off <<= 1) {
        int v = (t >= off) ? sh[t - off] : 0;
        __syncthreads();
        sh[t] += v;
        __syncthreads();
    }
    if (t < nb) partial[t] = (t == 0) ? 0 : sh[t - 1];
    if (t == 0) row_ptr[n] = e;
}

__global__ __launch_bounds__(256) void emit_kernel(const int* __restrict__ cnt,
                                                   const int* __restrict__ partial,
                                                   int* __restrict__ row_ptr,
                                                   int* __restrict__ cursor,
                                                   float* __restrict__ dinv, int n) {
    const int b = blockIdx.x, t = threadIdx.x;
    const int base = b * 1024 + t * 4;
    int4 c = make_int4(0, 0, 0, 0);
    if (base + 3 < n) {
        c = *(const int4*)(cnt + base);
    } else {
        if (base     < n) c.x = cnt[base];
        if (base + 1 < n) c.y = cnt[base + 1];
        if (base + 2 < n) c.z = cnt[base + 2];
        if (base + 3 < n) c.w = cnt[base + 3];
    }
    const int ts = c.x + c.y + c.z + c.w;
    int incl = ts;
    const int lane = t & 63;
    #pragma unroll
    for (int off = 1; off < 64; off <<= 1) {
        int v = __shfl_up(incl, off, 64);
        if (lane >= off) incl += v;
    }
    __shared__ int wsum[4];
    if (lane == 63) wsum[t >> 6] = incl;
    __syncthreads();
    const int w = t >> 6;
    int waveoff = 0;
    #pragma unroll
    for (int i = 0; i < 3; ++i) if (i < w) waveoff += wsum[i];
    const int basev = partial[b] + waveoff + (incl - ts);
    const int e0 = basev, e1 = e0 + c.x, e2 = e1 + c.y, e3 = e2 + c.z;
    if (base + 3 < n) {
        *(int4*)(row_ptr + base) = make_int4(e0, e1, e2, e3);
        *(int4*)(cursor  + base) = make_int4(e0, e1, e2, e3);
        *(float4*)(dinv + base) = make_float4(rsqrtf((float)(c.x + 1)), rsqrtf((float)(c.y + 1)),
                                              rsqrtf((float)(c.z + 1)), rsqrtf((float)(c.w + 1)));
    } else {
        int es[4] = {e0, e1, e2, e3};
        int cs[4] = {c.x, c.y, c.z, c.w};
        for (int j = 0; j < 4; ++j) if (base + j < n) {
            row_ptr[base + j] = es[j];
            cursor[base + j]  = es[j];
            dinv[base + j]    = rsqrtf((float)(cs[j] + 1));
        }
    }
}

__global__ void fill_kernel(const int* __restrict__ src, const int* __restrict__ dst,
                            int* __restrict__ cursor, int* __restrict__ col, int e) {
    int i = blockIdx.x * blockDim.x + threadIdx.x;
    if (i < e) {
        int p = atomicAdd(&cursor[dst[i]], 1);
        col[p] = src[i];
    }
}

// ---------------- W transpose+convert: Wt[l][n][k] = bf16(W[l][k][n]) ----------------
__global__ __launch_bounds__(256) void wt_prep_kernel(const float* __restrict__ W,
                                                      short* __restrict__ Wt, int total) {
    int o = blockIdx.x * blockDim.x + threadIdx.x;
    if (o >= total) return;
    int l = o >> 14;
    int r = o & 16383;
    int nn = r >> 7;
    int k  = r & 127;
    Wt[o] = f2bf(W[(size_t)l * 16384 + (size_t)k * 128 + nn]);
}

// ---------------- GEMM: H(bf16) = act @ W via bf16 MFMA ----------------
template <bool IN_F32>
__global__ __launch_bounds__(256) void gemm_mfma_kernel(const void* __restrict__ Xv,
                                                        const short* __restrict__ Wt,
                                                        short* __restrict__ H, int n) {
    __shared__ short Alds[64 * AST];
    __shared__ short Wlds[128 * AST];
    const int t = threadIdx.x;
    const int row0 = blockIdx.x * 64;

    #pragma unroll
    for (int i = 0; i < 8; ++i) {
        int q  = t + i * 256;
        int nn = q >> 4;
        int kc = q & 15;
        short8v v = *(const short8v*)(Wt + nn * 128 + kc * 8);
        *(short8v*)(&Wlds[nn * AST + kc * 8]) = v;
    }
    if constexpr (IN_F32) {
        const float* X = (const float*)Xv;
        #pragma unroll
        for (int i = 0; i < 8; ++i) {
            int q  = t + i * 256;
            int r  = q >> 5;
            int k4 = q & 31;
            int row = row0 + r;
            float4 v = make_float4(0.f, 0.f, 0.f, 0.f);
            if (row < n) v = *(const float4*)(X + (size_t)row * D_DIM + k4 * 4);
            short4v s;
            s.x = f2bf(v.x); s.y = f2bf(v.y); s.z = f2bf(v.z); s.w = f2bf(v.w);
            *(short4v*)(&Alds[r * AST + k4 * 4]) = s;
        }
    } else {
        const short* X = (const short*)Xv;
        #pragma unroll
        for (int i = 0; i < 4; ++i) {
            int q  = t + i * 256;
            int r  = q >> 4;
            int kc = q & 15;
            int row = row0 + r;
            short8v v = {0,0,0,0,0,0,0,0};
            if (row < n) v = *(const short8v*)(X + (size_t)row * D_DIM + kc * 8);
            *(short8v*)(&Alds[r * AST + kc * 8]) = v;
        }
    }
    __syncthreads();

    const int wv   = t >> 6;
    const int lane = t & 63;
    const int m    = lane & 15;
    const int quad = lane >> 4;

    const short* abase = &Alds[(wv * 16 + m) * AST + quad * 8];
    const short* bbase = &Wlds[m * AST + quad * 8];

    short8v afr[4];
    #pragma unroll
    for (int kt = 0; kt < 4; ++kt) afr[kt] = *(const short8v*)(abase + kt * 32);

    floatx4 acc[8];
    #pragma unroll
    for (int c = 0; c < 8; ++c) acc[c] = (floatx4){0.f, 0.f, 0.f, 0.f};

    #pragma unroll
    for (int c = 0; c < 8; ++c) {
        #pragma unroll
        for (int kt = 0; kt < 4; ++kt) {
            short8v bfr = *(const short8v*)(bbase + c * 16 * AST + kt * 32);
            acc[c] = __builtin_amdgcn_mfma_f32_16x16x32_bf16(afr[kt], bfr, acc[c], 0, 0, 0);
        }
    }

    #pragma unroll
    for (int c = 0; c < 8; ++c) {
        #pragma unroll
        for (int r = 0; r < 4; ++r) {
            int row = row0 + wv * 16 + quad * 4 + r;
            if (row < n) H[(size_t)row * D_DIM + c * 16 + m] = f2bf(acc[c][r]);
        }
    }
}

// ---------------- Aggregation + bias + ReLU + LayerNorm ----------------
// One wave per node-group (NPW nodes). Lane-parallel edge metadata; half-wave
// (32 lanes x 8B) row gathers, 4 rows in flight per iteration.
template <bool OUT_BF16>
__global__ __launch_bounds__(256) void agg_kernel(const short* __restrict__ Hb,
                                                  const int* __restrict__ row_ptr,
                                                  const int* __restrict__ col,
                                                  const float* __restrict__ dinv,
                                                  const float* __restrict__ bias,
                                                  const float* __restrict__ gamma,
                                                  const float* __restrict__ beta,
                                                  void* __restrict__ Yv, int n) {
    const int wave = threadIdx.x >> 6;
    const int lane = threadIdx.x & 63;
    const int half = lane >> 5;
    const int l32  = lane & 31;
    const int v0   = (blockIdx.x * 4 + wave) * NPW;
    if (v0 >= n) return;
    const int vend = min(v0 + NPW, n);

    // per-lane column slice: cols [4*l32, 4*l32+4)
    const float4 bb = ((const float4*)bias)[l32];
    const float4 gg = ((const float4*)gamma)[l32];
    const float4 be = ((const float4*)beta)[l32];

    for (int v = v0; v < vend; ++v) {
        const float dv  = dinv[v];
        const int   beg = row_ptr[v];
        const int   total = (row_ptr[v + 1] - beg) + 1;   // +1 for self-loop (item 0)

        float a0 = 0.f, a1 = 0.f, a2 = 0.f, a3 = 0.f;

        for (int c = 0; c < total; c += 64) {
            const int cnt = min(64, total - c);
            // lane-parallel metadata: item 0 = self, item j>0 = edge j-1
            int   u  = v;
            float wt = 0.f;
            const int item = c + lane;
            if (lane < cnt) {
                if (item == 0) {
                    wt = dv * dv;
                } else {
                    u  = col[beg + item - 1];
                    wt = dinv[u] * dv;
                }
            }
            // consume 4 items/iteration: half-wave h takes items j+h, j+2+h
            const int loop = (cnt + 3) & ~3;
            for (int j = 0; j < loop; j += 4) {
                const int ea = j + half;
                const int eb = j + 2 + half;
                const int   ua = __shfl(u, ea, 64);
                const float wa = __shfl(wt, ea, 64);
                const int   ub = __shfl(u, eb, 64);
                const float wb = __shfl(wt, eb, 64);
                const uint2 pa = *(const uint2*)(Hb + (size_t)ua * D_DIM + l32 * 4);
                const uint2 pb = *(const uint2*)(Hb + (size_t)ub * D_DIM + l32 * 4);
                a0 = fmaf(wa, bflo(pa.x), a0);
                a1 = fmaf(wa, bfhi(pa.x), a1);
                a2 = fmaf(wa, bflo(pa.y), a2);
                a3 = fmaf(wa, bfhi(pa.y), a3);
                a0 = fmaf(wb, bflo(pb.x), a0);
                a1 = fmaf(wb, bfhi(pb.x), a1);
                a2 = fmaf(wb, bflo(pb.y), a2);
                a3 = fmaf(wb, bfhi(pb.y), a3);
            }
        }

        // merge the two half-wave accumulators
        a0 += __shfl_xor(a0, 32, 64);
        a1 += __shfl_xor(a1, 32, 64);
        a2 += __shfl_xor(a2, 32, 64);
        a3 += __shfl_xor(a3, 32, 64);

        // bias + relu
        a0 = fmaxf(a0 + bb.x, 0.f);
        a1 = fmaxf(a1 + bb.y, 0.f);
        a2 = fmaxf(a2 + bb.z, 0.f);
        a3 = fmaxf(a3 + bb.w, 0.f);

        // layernorm over 128 values (4 per lane across a 32-lane group)
        float s1 = a0 + a1 + a2 + a3;
        float s2 = a0 * a0 + a1 * a1 + a2 * a2 + a3 * a3;
        #pragma unroll
        for (int m = 1; m < 32; m <<= 1) {
            s1 += __shfl_xor(s1, m, 64);
            s2 += __shfl_xor(s2, m, 64);
        }
        const float mu  = s1 * (1.f / 128.f);
        const float var = s2 * (1.f / 128.f) - mu * mu;
        const float rs  = rsqrtf(var + 1e-5f);

        const float o0 = (a0 - mu) * rs * gg.x + be.x;
        const float o1 = (a1 - mu) * rs * gg.y + be.y;
        const float o2 = (a2 - mu) * rs * gg.z + be.z;
        const float o3 = (a3 - mu) * rs * gg.w + be.w;

        if (half == 0) {
            if constexpr (OUT_BF16) {
                uint2 pk;
                pk.x = (unsigned)(unsigned short)f2bf(o0) |
                       ((unsigned)(unsigned short)f2bf(o1) << 16);
                pk.y = (unsigned)(unsigned short)f2bf(o2) |
                       ((unsigned)(unsigned short)f2bf(o3) << 16);
                ((uint2*)((short*)Yv + (size_t)v * D_DIM))[l32] = pk;
            } else {
                float4 o; o.x = o0; o.y = o1; o.z = o2; o.w = o3;
                ((float4*)((float*)Yv + (size_t)v * D_DIM))[l32] = o;
            }
        }
    }
}

// ---------------- launch ----------------

extern "C" void kernel_launch(void* const* d_in, const int* in_sizes, int n_in,
                              void* d_out, int out_size, void* d_ws, size_t ws_size,
                              hipStream_t stream) {
    const float* x     = (const float*)d_in[0];
    const float* W     = (const float*)d_in[1];
    const float* bias  = (const float*)d_in[2];
    const float* gamma = (const float*)d_in[3];
    const float* beta  = (const float*)d_in[4];
    const int*   edges = (const int*)d_in[5];

    const int N = in_sizes[0] / D_DIM;
    const int E = in_sizes[5] / 2;
    const int L = in_sizes[1] / (D_DIM * D_DIM);

    const int* src = edges;
    const int* dst = edges + E;

    const int NB = (N + 1023) / 1024;

    // workspace carve — 16B alignment maintained
    char* w = (char*)d_ws;
    short* Hb   = (short*)w; w += (size_t)N * D_DIM * sizeof(short);
    short* Act  = (short*)w; w += (size_t)N * D_DIM * sizeof(short);
    int* cnt     = (int*)w;  w += (size_t)((N + 3) & ~3) * sizeof(int);
    int* row_ptr = (int*)w;  w += (size_t)((N + 4) & ~3) * sizeof(int);
    int* cursor  = (int*)w;  w += (size_t)((N + 3) & ~3) * sizeof(int);
    int* colArr  = (int*)w;  w += (size_t)((E + 3) & ~3) * sizeof(int);
    float* dinv  = (float*)w; w += (size_t)((N + 3) & ~3) * sizeof(float);
    int* partial = (int*)w;  w += (size_t)((NB + 3) & ~3) * sizeof(int);
    short* Wt    = (short*)w; w += (size_t)L * D_DIM * D_DIM * sizeof(short);

    // CSR build
    zero_cnt_kernel<<<(N + 255) / 256, 256, 0, stream>>>(cnt, N);
    count_kernel<<<(E + 255) / 256, 256, 0, stream>>>(dst, cnt, E);
    partial_kernel<<<NB, 256, 0, stream>>>(cnt, partial, N);
    scan_partials_kernel<<<1, 1024, 0, stream>>>(partial, NB, row_ptr, N, E);
    emit_kernel<<<NB, 256, 0, stream>>>(cnt, partial, row_ptr, cursor, dinv, N);
    fill_kernel<<<(E + 255) / 256, 256, 0, stream>>>(src, dst, cursor, colArr, E);

    // W -> bf16 transpose (once per call)
    const int WT_TOTAL = L * D_DIM * D_DIM;
    wt_prep_kernel<<<(WT_TOTAL + 255) / 256, 256, 0, stream>>>(W, Wt, WT_TOTAL);

    const int GB = (N + 63) / 64;
    const int AB = (N + 4 * NPW - 1) / (4 * NPW);

    // layer 0: f32 x -> H(bf16) -> Act(bf16)
    gemm_mfma_kernel<true><<<GB, 256, 0, stream>>>(x, Wt, Hb, N);
    agg_kernel<true><<<AB, 256, 0, stream>>>(Hb, row_ptr, colArr, dinv,
                                             bias, gamma, beta, Act, N);
    // layers 1..L-2: bf16 -> bf16
    for (int l = 1; l < L - 1; ++l) {
        gemm_mfma_kernel<false><<<GB, 256, 0, stream>>>(Act, Wt + (size_t)l * D_DIM * D_DIM, Hb, N);
        agg_kernel<true><<<AB, 256, 0, stream>>>(Hb, row_ptr, colArr, dinv,
                                                 bias + (size_t)l * D_DIM,
                                                 gamma + (size_t)l * D_DIM,
                                                 beta + (size_t)l * D_DIM, Act, N);
    }
    // final layer: bf16 -> f32 d_out
    {
        int l = L - 1;
        gemm_mfma_kernel<false><<<GB, 256, 0, stream>>>(Act, Wt + (size_t)l * D_DIM * D_DIM, Hb, N);
        agg_kernel<false><<<AB, 256, 0, stream>>>(Hb, row_ptr, colArr, dinv,
                                                  bias + (size_t)l * D_DIM,
                                                  gamma + (size_t)l * D_DIM,
                                                  beta + (size_t)l * D_DIM, d_out, N);
    }
}

// Round 6
// 394.904 us; speedup vs baseline: 2.4469x; 1.0822x over previous
//
#include <hip/hip_runtime.h>
#include <hip/hip_bf16.h>

#define D_DIM 128
#define AST 136   // padded LDS row stride (shorts)

typedef __attribute__((ext_vector_type(8))) short short8v;
typedef __attribute__((ext_vector_type(4))) short short4v;
typedef __attribute__((ext_vector_type(4))) float floatx4;

__device__ __forceinline__ short f2bf(float x) {
    unsigned u = __builtin_bit_cast(unsigned, x);
    unsigned r = u + 0x7fff + ((u >> 16) & 1);   // RNE
    return (short)(r >> 16);
}
__device__ __forceinline__ float bflo(unsigned p) {
    return __builtin_bit_cast(float, p << 16);
}
__device__ __forceinline__ float bfhi(unsigned p) {
    return __builtin_bit_cast(float, p & 0xffff0000u);
}

// ---------------- CSR build ----------------

__global__ void zero_cnt_kernel(int* __restrict__ cnt, int n) {
    int i = blockIdx.x * blockDim.x + threadIdx.x;
    if (i < n) cnt[i] = 0;
}

__global__ void count_kernel(const int* __restrict__ dst, int* __restrict__ cnt, int e) {
    int i = blockIdx.x * blockDim.x + threadIdx.x;
    if (i < e) atomicAdd(&cnt[dst[i]], 1);
}

__global__ __launch_bounds__(256) void partial_kernel(const int* __restrict__ cnt,
                                                      int* __restrict__ partial, int n) {
    const int b = blockIdx.x, t = threadIdx.x;
    const int base = b * 1024 + t * 4;
    int s = 0;
    if (base + 3 < n) {
        int4 c = *(const int4*)(cnt + base);
        s = c.x + c.y + c.z + c.w;
    } else {
        for (int j = 0; j < 4; ++j) if (base + j < n) s += cnt[base + j];
    }
    #pragma unroll
    for (int m = 1; m < 64; m <<= 1) s += __shfl_xor(s, m, 64);
    __shared__ int ws[4];
    if ((t & 63) == 0) ws[t >> 6] = s;
    __syncthreads();
    if (t == 0) partial[b] = ws[0] + ws[1] + ws[2] + ws[3];
}

__global__ __launch_bounds__(1024) void scan_partials_kernel(int* __restrict__ partial, int nb,
                                                             int* __restrict__ row_ptr,
                                                             int n, int e) {
    __shared__ int sh[1024];
    const int t = threadIdx.x;
    sh[t] = (t < nb) ? partial[t] : 0;
    __syncthreads();
    for (int off = 1; off < 1024; off <<= 1) {
        int v = (t >= off) ? sh[t - off] : 0;
        __syncthreads();
        sh[t] += v;
        __syncthreads();
    }
    if (t < nb) partial[t] = (t == 0) ? 0 : sh[t - 1];
    if (t == 0) row_ptr[n] = e;
}

__global__ __launch_bounds__(256) void emit_kernel(const int* __restrict__ cnt,
                                                   const int* __restrict__ partial,
                                                   int* __restrict__ row_ptr,
                                                   int* __restrict__ cursor,
                                                   float* __restrict__ dinv, int n) {
    const int b = blockIdx.x, t = threadIdx.x;
    const int base = b * 1024 + t * 4;
    int4 c = make_int4(0, 0, 0, 0);
    if (base + 3 < n) {
        c = *(const int4*)(cnt + base);
    } else {
        if (base     < n) c.x = cnt[base];
        if (base + 1 < n) c.y = cnt[base + 1];
        if (base + 2 < n) c.z = cnt[base + 2];
        if (base + 3 < n) c.w = cnt[base + 3];
    }
    const int ts = c.x + c.y + c.z + c.w;
    int incl = ts;
    const int lane = t & 63;
    #pragma unroll
    for (int off = 1; off < 64; off <<= 1) {
        int v = __shfl_up(incl, off, 64);
        if (lane >= off) incl += v;
    }
    __shared__ int wsum[4];
    if (lane == 63) wsum[t >> 6] = incl;
    __syncthreads();
    const int w = t >> 6;
    int waveoff = 0;
    #pragma unroll
    for (int i = 0; i < 3; ++i) if (i < w) waveoff += wsum[i];
    const int basev = partial[b] + waveoff + (incl - ts);
    const int e0 = basev, e1 = e0 + c.x, e2 = e1 + c.y, e3 = e2 + c.z;
    if (base + 3 < n) {
        *(int4*)(row_ptr + base) = make_int4(e0, e1, e2, e3);
        *(int4*)(cursor  + base) = make_int4(e0, e1, e2, e3);
        *(float4*)(dinv + base) = make_float4(rsqrtf((float)(c.x + 1)), rsqrtf((float)(c.y + 1)),
                                              rsqrtf((float)(c.z + 1)), rsqrtf((float)(c.w + 1)));
    } else {
        int es[4] = {e0, e1, e2, e3};
        int cs[4] = {c.x, c.y, c.z, c.w};
        for (int j = 0; j < 4; ++j) if (base + j < n) {
            row_ptr[base + j] = es[j];
            cursor[base + j]  = es[j];
            dinv[base + j]    = rsqrtf((float)(cs[j] + 1));
        }
    }
}

// fill CSR with precomputed per-edge weight: meta = {src, dinv[src]*dinv[dst]}
__global__ void fill_kernel(const int* __restrict__ src, const int* __restrict__ dst,
                            const float* __restrict__ dinv,
                            int* __restrict__ cursor, int2* __restrict__ meta, int e) {
    int i = blockIdx.x * blockDim.x + threadIdx.x;
    if (i < e) {
        int s = src[i], d = dst[i];
        int p = atomicAdd(&cursor[d], 1);
        float w = dinv[s] * dinv[d];
        meta[p] = make_int2(s, __builtin_bit_cast(int, w));
    }
}

// ---------------- W transpose+convert: Wt[l][n][k] = bf16(W[l][k][n]) ----------------
__global__ __launch_bounds__(256) void wt_prep_kernel(const float* __restrict__ W,
                                                      short* __restrict__ Wt, int total) {
    int o = blockIdx.x * blockDim.x + threadIdx.x;
    if (o >= total) return;
    int l = o >> 14;
    int r = o & 16383;
    int nn = r >> 7;
    int k  = r & 127;
    Wt[o] = f2bf(W[(size_t)l * 16384 + (size_t)k * 128 + nn]);
}

// ---------------- GEMM: H(bf16) = act @ W via bf16 MFMA ----------------
template <bool IN_F32>
__global__ __launch_bounds__(256) void gemm_mfma_kernel(const void* __restrict__ Xv,
                                                        const short* __restrict__ Wt,
                                                        short* __restrict__ H, int n) {
    __shared__ short Alds[64 * AST];
    __shared__ short Wlds[128 * AST];
    const int t = threadIdx.x;
    const int row0 = blockIdx.x * 64;

    #pragma unroll
    for (int i = 0; i < 8; ++i) {
        int q  = t + i * 256;
        int nn = q >> 4;
        int kc = q & 15;
        short8v v = *(const short8v*)(Wt + nn * 128 + kc * 8);
        *(short8v*)(&Wlds[nn * AST + kc * 8]) = v;
    }
    if constexpr (IN_F32) {
        const float* X = (const float*)Xv;
        #pragma unroll
        for (int i = 0; i < 8; ++i) {
            int q  = t + i * 256;
            int r  = q >> 5;
            int k4 = q & 31;
            int row = row0 + r;
            float4 v = make_float4(0.f, 0.f, 0.f, 0.f);
            if (row < n) v = *(const float4*)(X + (size_t)row * D_DIM + k4 * 4);
            short4v s;
            s.x = f2bf(v.x); s.y = f2bf(v.y); s.z = f2bf(v.z); s.w = f2bf(v.w);
            *(short4v*)(&Alds[r * AST + k4 * 4]) = s;
        }
    } else {
        const short* X = (const short*)Xv;
        #pragma unroll
        for (int i = 0; i < 4; ++i) {
            int q  = t + i * 256;
            int r  = q >> 4;
            int kc = q & 15;
            int row = row0 + r;
            short8v v = {0,0,0,0,0,0,0,0};
            if (row < n) v = *(const short8v*)(X + (size_t)row * D_DIM + kc * 8);
            *(short8v*)(&Alds[r * AST + kc * 8]) = v;
        }
    }
    __syncthreads();

    const int wv   = t >> 6;
    const int lane = t & 63;
    const int m    = lane & 15;
    const int quad = lane >> 4;

    const short* abase = &Alds[(wv * 16 + m) * AST + quad * 8];
    const short* bbase = &Wlds[m * AST + quad * 8];

    short8v afr[4];
    #pragma unroll
    for (int kt = 0; kt < 4; ++kt) afr[kt] = *(const short8v*)(abase + kt * 32);

    floatx4 acc[8];
    #pragma unroll
    for (int c = 0; c < 8; ++c) acc[c] = (floatx4){0.f, 0.f, 0.f, 0.f};

    #pragma unroll
    for (int c = 0; c < 8; ++c) {
        #pragma unroll
        for (int kt = 0; kt < 4; ++kt) {
            short8v bfr = *(const short8v*)(bbase + c * 16 * AST + kt * 32);
            acc[c] = __builtin_amdgcn_mfma_f32_16x16x32_bf16(afr[kt], bfr, acc[c], 0, 0, 0);
        }
    }

    #pragma unroll
    for (int c = 0; c < 8; ++c) {
        #pragma unroll
        for (int r = 0; r < 4; ++r) {
            int row = row0 + wv * 16 + quad * 4 + r;
            if (row < n) H[(size_t)row * D_DIM + c * 16 + m] = f2bf(acc[c][r]);
        }
    }
}

// ---------------- Aggregation + bias + ReLU + LayerNorm ----------------
// One wave per node (v wave-uniform -> scalar metadata loads, SGPR weights).
// Edge loop unrolled x4: 4 independent 256B row gathers in flight.
template <bool OUT_BF16>
__global__ __launch_bounds__(256) void agg_kernel(const short* __restrict__ Hb,
                                                  const int* __restrict__ row_ptr,
                                                  const int2* __restrict__ meta,
                                                  const float* __restrict__ dinv,
                                                  const float* __restrict__ bias,
                                                  const float* __restrict__ gamma,
                                                  const float* __restrict__ beta,
                                                  void* __restrict__ Yv, int n) {
    const int wave = __builtin_amdgcn_readfirstlane(threadIdx.x >> 6);
    const int lane = threadIdx.x & 63;
    const int v = blockIdx.x * 4 + wave;
    if (v >= n) return;

    const float dv = dinv[v];                    // uniform -> s_load
    const int beg = row_ptr[v];
    const int end = row_ptr[v + 1];

    // self loop
    const unsigned ps = ((const unsigned*)(Hb + (size_t)v * D_DIM))[lane];
    const float wself = dv * dv;
    float ax = bflo(ps) * wself;
    float ay = bfhi(ps) * wself;

    int i = beg;
    for (; i + 4 <= end; i += 4) {
        // wave-uniform metadata -> s_load_dwordx8; weights live in SGPRs
        const int2 m0 = meta[i];
        const int2 m1 = meta[i + 1];
        const int2 m2 = meta[i + 2];
        const int2 m3 = meta[i + 3];
        // 4 independent coalesced row gathers (issued before any use)
        const unsigned p0 = ((const unsigned*)(Hb + (size_t)m0.x * D_DIM))[lane];
        const unsigned p1 = ((const unsigned*)(Hb + (size_t)m1.x * D_DIM))[lane];
        const unsigned p2 = ((const unsigned*)(Hb + (size_t)m2.x * D_DIM))[lane];
        const unsigned p3 = ((const unsigned*)(Hb + (size_t)m3.x * D_DIM))[lane];
        const float w0 = __builtin_bit_cast(float, m0.y);
        const float w1 = __builtin_bit_cast(float, m1.y);
        const float w2 = __builtin_bit_cast(float, m2.y);
        const float w3 = __builtin_bit_cast(float, m3.y);
        ax = fmaf(w0, bflo(p0), ax);  ay = fmaf(w0, bfhi(p0), ay);
        ax = fmaf(w1, bflo(p1), ax);  ay = fmaf(w1, bfhi(p1), ay);
        ax = fmaf(w2, bflo(p2), ax);  ay = fmaf(w2, bfhi(p2), ay);
        ax = fmaf(w3, bflo(p3), ax);  ay = fmaf(w3, bfhi(p3), ay);
    }
    for (; i < end; ++i) {
        const int2 m0 = meta[i];
        const unsigned p0 = ((const unsigned*)(Hb + (size_t)m0.x * D_DIM))[lane];
        const float w0 = __builtin_bit_cast(float, m0.y);
        ax = fmaf(w0, bflo(p0), ax);
        ay = fmaf(w0, bfhi(p0), ay);
    }

    // bias + relu
    const float2 bb = ((const float2*)bias)[lane];
    float a0 = fmaxf(ax + bb.x, 0.f);
    float a1 = fmaxf(ay + bb.y, 0.f);

    // layernorm over 128 values (2 per lane, 64-lane butterfly)
    float s1 = a0 + a1;
    float s2 = a0 * a0 + a1 * a1;
    #pragma unroll
    for (int m = 1; m < 64; m <<= 1) {
        s1 += __shfl_xor(s1, m, 64);
        s2 += __shfl_xor(s2, m, 64);
    }
    const float mu  = s1 * (1.f / 128.f);
    const float var = s2 * (1.f / 128.f) - mu * mu;
    const float rs  = rsqrtf(var + 1e-5f);

    const float2 gg = ((const float2*)gamma)[lane];
    const float2 be = ((const float2*)beta)[lane];
    const float o0 = (a0 - mu) * rs * gg.x + be.x;
    const float o1 = (a1 - mu) * rs * gg.y + be.y;

    if constexpr (OUT_BF16) {
        unsigned pack = (unsigned)(unsigned short)f2bf(o0) |
                        ((unsigned)(unsigned short)f2bf(o1) << 16);
        ((unsigned*)((short*)Yv + (size_t)v * D_DIM))[lane] = pack;
    } else {
        float2 o; o.x = o0; o.y = o1;
        ((float2*)((float*)Yv + (size_t)v * D_DIM))[lane] = o;
    }
}

// ---------------- launch ----------------

extern "C" void kernel_launch(void* const* d_in, const int* in_sizes, int n_in,
                              void* d_out, int out_size, void* d_ws, size_t ws_size,
                              hipStream_t stream) {
    const float* x     = (const float*)d_in[0];
    const float* W     = (const float*)d_in[1];
    const float* bias  = (const float*)d_in[2];
    const float* gamma = (const float*)d_in[3];
    const float* beta  = (const float*)d_in[4];
    const int*   edges = (const int*)d_in[5];

    const int N = in_sizes[0] / D_DIM;
    const int E = in_sizes[5] / 2;
    const int L = in_sizes[1] / (D_DIM * D_DIM);

    const int* src = edges;
    const int* dst = edges + E;

    const int NB = (N + 1023) / 1024;

    // workspace carve — 16B alignment maintained
    char* w = (char*)d_ws;
    short* Hb   = (short*)w; w += (size_t)N * D_DIM * sizeof(short);
    short* Act  = (short*)w; w += (size_t)N * D_DIM * sizeof(short);
    int* cnt     = (int*)w;  w += (size_t)((N + 3) & ~3) * sizeof(int);
    int* row_ptr = (int*)w;  w += (size_t)((N + 4) & ~3) * sizeof(int);
    int* cursor  = (int*)w;  w += (size_t)((N + 3) & ~3) * sizeof(int);
    int2* meta   = (int2*)w; w += (size_t)E * sizeof(int2);
    float* dinv  = (float*)w; w += (size_t)((N + 3) & ~3) * sizeof(float);
    int* partial = (int*)w;  w += (size_t)((NB + 3) & ~3) * sizeof(int);
    short* Wt    = (short*)w; w += (size_t)L * D_DIM * D_DIM * sizeof(short);

    // CSR build
    zero_cnt_kernel<<<(N + 255) / 256, 256, 0, stream>>>(cnt, N);
    count_kernel<<<(E + 255) / 256, 256, 0, stream>>>(dst, cnt, E);
    partial_kernel<<<NB, 256, 0, stream>>>(cnt, partial, N);
    scan_partials_kernel<<<1, 1024, 0, stream>>>(partial, NB, row_ptr, N, E);
    emit_kernel<<<NB, 256, 0, stream>>>(cnt, partial, row_ptr, cursor, dinv, N);
    fill_kernel<<<(E + 255) / 256, 256, 0, stream>>>(src, dst, dinv, cursor, meta, E);

    // W -> bf16 transpose (once per call)
    const int WT_TOTAL = L * D_DIM * D_DIM;
    wt_prep_kernel<<<(WT_TOTAL + 255) / 256, 256, 0, stream>>>(W, Wt, WT_TOTAL);

    const int GB = (N + 63) / 64;
    const int AB = (N + 3) / 4;

    // layer 0: f32 x -> H(bf16) -> Act(bf16)
    gemm_mfma_kernel<true><<<GB, 256, 0, stream>>>(x, Wt, Hb, N);
    agg_kernel<true><<<AB, 256, 0, stream>>>(Hb, row_ptr, meta, dinv,
                                             bias, gamma, beta, Act, N);
    // layers 1..L-2: bf16 -> bf16
    for (int l = 1; l < L - 1; ++l) {
        gemm_mfma_kernel<false><<<GB, 256, 0, stream>>>(Act, Wt + (size_t)l * D_DIM * D_DIM, Hb, N);
        agg_kernel<true><<<AB, 256, 0, stream>>>(Hb, row_ptr, meta, dinv,
                                                 bias + (size_t)l * D_DIM,
                                                 gamma + (size_t)l * D_DIM,
                                                 beta + (size_t)l * D_DIM, Act, N);
    }
    // final layer: bf16 -> f32 d_out
    {
        int l = L - 1;
        gemm_mfma_kernel<false><<<GB, 256, 0, stream>>>(Act, Wt + (size_t)l * D_DIM * D_DIM, Hb, N);
        agg_kernel<false><<<AB, 256, 0, stream>>>(Hb, row_ptr, meta, dinv,
                                                  bias + (size_t)l * D_DIM,
                                                  gamma + (size_t)l * D_DIM,
                                                  beta + (size_t)l * D_DIM, d_out, N);
    }
}